// Round 8
// baseline (70.474 us; speedup 1.0000x reference)
//
#include <hip/hip_runtime.h>
#include <hip/hip_bf16.h>

#define B_ 2048
#define D_ 17
#define H_ 8
#define HID_ 256
#define OUT_ 23
#define XROW 8721       /* 513*17 floats per batch */
#define SEQN 8704       /* 512*17 seq floats per batch */
#define NB 4            /* batches per attn block */

__device__ __forceinline__ float4 ld4u(const float* p) {   // 4B-aligned 16B load
  float4 v; __builtin_memcpy(&v, p, 16); return v;
}
__device__ __forceinline__ float bclane(float v, int l) {  // wave broadcast via readlane (no LDS pipe)
  return __uint_as_float(__builtin_amdgcn_readlane(__float_as_uint(v), l));
}

// ---------------- Kernel 1: prep — transpose W2s + fold q into Wk ----------------
__global__ __launch_bounds__(256) void prep_kernel(
    const float* __restrict__ pW2, const float* __restrict__ vW2,
    const float* __restrict__ Wk, const float* __restrict__ bk,
    const float* __restrict__ q,
    float* __restrict__ pW2t, float* __restrict__ vW2t, float* __restrict__ qkc)
{
  const int bid = blockIdx.x;
  const int t = threadIdx.x;
  if (bid == 128) {
    if (t < H_ * D_) {
      const int h = t / D_, dd = t - h * D_;
      float s = 0.f;
      #pragma unroll
      for (int e = 0; e < D_; ++e) s = fmaf(Wk[h*289 + e*D_ + dd], q[h*D_ + e], s);
      qkc[h*18 + dd] = s;
    } else if (t < H_ * D_ + H_) {
      const int h = t - H_ * D_;
      float s = 0.f;
      #pragma unroll
      for (int e = 0; e < D_; ++e) s = fmaf(bk[h*D_ + e], q[h*D_ + e], s);
      qkc[h*18 + 17] = s;
    }
    return;
  }
  __shared__ float tile[32][33];
  const int m = bid >> 6, tid = bid & 63;
  const int ti = (tid >> 3) * 32, tk = (tid & 7) * 32;
  const float* src = m ? vW2 : pW2;
  float* dst = m ? vW2t : pW2t;
  const int tx = t & 31, ty = t >> 5;
  #pragma unroll
  for (int r = 0; r < 4; ++r) tile[ty + 8*r][tx] = src[(ti + ty + 8*r)*HID_ + tk + tx];
  __syncthreads();
  #pragma unroll
  for (int r = 0; r < 4; ++r) dst[(tk + ty + 8*r)*HID_ + ti + tx] = tile[tx][ty + 8*r];
}

// ---------------- Kernel 2: pipelined LDS attention -> comb ----------------
// 512 thr = 8 waves; NB=4 batches per block, double-buffered LDS. Grid 512 = 2 blocks/CU,
// ALL resident (one generation). Per iter: issue batch j+1 global loads -> compute batch j
// -> barrier -> ds_write j+1 -> finish j. Probe all 4 lengths up front (wave w -> batch w).
__global__ __launch_bounds__(512, 4) void attn_comb_kernel(
    const float* __restrict__ x, const float* __restrict__ qkc,
    const float* __restrict__ Wv, const float* __restrict__ bv,
    const float* __restrict__ Wo, const float* __restrict__ bo,
    float* __restrict__ comb)
{
  __shared__ __align__(16) float s_buf[2][SEQN];
  __shared__ float s_part[8][H_][18];
  __shared__ float s_swn[H_ * D_];
  __shared__ float s_agg[H_ * D_];
  __shared__ float s_wp[136];
  __shared__ int s_nr[NB];

  const int t = threadIdx.x;
  const int w = t >> 6, lane = t & 63;
  const int h = lane & 7, rg = lane >> 3;
  const int b0 = blockIdx.x * NB;

  // ---- probe lengths (masked tail rows are exact zeros; live word0==0 has P~1e-45)
  if (w < NB) {
    const float* xs = x + (size_t)(b0 + w) * XROW + D_;
    const float pv = xs[lane * 136];
    unsigned long long live = __ballot(pv != 0.f) | 1ull;
    if (lane == 0) s_nr[w] = 8 * (64 - __builtin_clzll(live));   // len <= nr <= len+7
  }

  float qk[D_];
  #pragma unroll
  for (int d = 0; d < D_; ++d) qk[d] = qkc[h*18 + d];
  const float chr = qkc[h*18 + 17];

  __syncthreads();

  // ---- stage batch 0 into buf 0 (live rounds only)
  {
    const int rnd = (s_nr[0] * D_ + 2047) >> 11;
    const float* xs = x + (size_t)b0 * XROW + D_;
    float4 st[5];
    #pragma unroll
    for (int r = 0; r < 5; ++r) if (r < rnd) {
      int off = ((r << 9) + t) << 2; if (off > SEQN - 4) off = SEQN - 4;
      st[r] = ld4u(xs + off);
    }
    #pragma unroll
    for (int r = 0; r < 5; ++r) if (r < rnd) {
      int off = ((r << 9) + t) << 2; if (off > SEQN - 4) off = SEQN - 4;
      *(float4*)&s_buf[0][off] = st[r];
    }
  }
  __syncthreads();

  #pragma unroll 1
  for (int j = 0; j < NB; ++j) {
    // ---- issue next batch's loads early (latency hides under compute+finish)
    float4 st[5]; int rnd1 = 0;
    if (j + 1 < NB) {
      rnd1 = (s_nr[j+1] * D_ + 2047) >> 11;
      const float* xs = x + (size_t)(b0 + j + 1) * XROW + D_;
      #pragma unroll
      for (int r = 0; r < 5; ++r) if (r < rnd1) {
        int off = ((r << 9) + t) << 2; if (off > SEQN - 4) off = SEQN - 4;
        st[r] = ld4u(xs + off);
      }
    }

    // ---- compute batch j from s_buf[j&1]
    const int ng = s_nr[j] >> 2;              // live granules (4 rows each)
    const float* sb = s_buf[j & 1];
    float den = 0.f, acc[D_];
    #pragma unroll
    for (int d = 0; d < D_; ++d) acc[d] = 0.f;

    auto dorow = [&](const float* r, bool ok) {
      float sc = chr;
      #pragma unroll
      for (int d = 0; d < D_; ++d) sc = fmaf(qk[d], r[d], sc);
      const float p = (ok && r[0] != 0.f) ? __expf(sc) : 0.f;
      den += p;
      #pragma unroll
      for (int d = 0; d < D_; ++d) acc[d] = fmaf(p, r[d], acc[d]);
    };
    auto dogran = [&](int g, bool ok) {
      const float* gb = sb + (ok ? g : 0) * 68;   // granule: 4 rows = 68 floats, 16B aligned
      {
        float f[36];
        #pragma unroll
        for (int i = 0; i < 9; ++i) {
          const float4 v = *(const float4*)(gb + 4*i);
          f[4*i] = v.x; f[4*i+1] = v.y; f[4*i+2] = v.z; f[4*i+3] = v.w;
        }
        dorow(&f[0], ok); dorow(&f[17], ok);
      }
      {
        float f[36];
        #pragma unroll
        for (int i = 0; i < 9; ++i) {
          const float4 v = *(const float4*)(gb + 32 + 4*i);
          f[4*i] = v.x; f[4*i+1] = v.y; f[4*i+2] = v.z; f[4*i+3] = v.w;
        }
        dorow(&f[2], ok); dorow(&f[19], ok);
      }
    };
    {
      const int g = w * 8 + rg;                  // 8 waves x 8 rowgroups = 64 granules/pass
      dogran(g, g < ng);
    }
    if (w * 8 + 64 < ng) {                       // second pass needed only for ng > 64+w*8
      const int g = w * 8 + rg + 64;
      dogran(g, g < ng);
    }

    // ---- reduce 8 rowgroup-lanes per head
    #pragma unroll
    for (int m = 8; m <= 32; m <<= 1) {
      den += __shfl_xor(den, m, 64);
      #pragma unroll
      for (int d = 0; d < D_; ++d) acc[d] += __shfl_xor(acc[d], m, 64);
    }
    if (lane < 8) {
      float* pp = &s_part[w][lane][0];
      pp[0] = den;
      #pragma unroll
      for (int d = 0; d < D_; ++d) pp[1 + d] = acc[d];
    }
    __syncthreads();                 // (1) s_part ready; buf[(j+1)&1] free (batch j-1 done)

    // ---- write next batch into the other buffer (loads issued long ago)
    if (j + 1 < NB) {
      #pragma unroll
      for (int r = 0; r < 5; ++r) if (r < rnd1) {
        int off = ((r << 9) + t) << 2; if (off > SEQN - 4) off = SEQN - 4;
        *(float4*)&s_buf[(j + 1) & 1][off] = st[r];
      }
    }

    // ---- finish batch j (low-thread phases overlap the ds_writes above)
    if (t < 136) {
      const int hh = t / D_, d = t - hh * D_;
      float dn = 0.f, ac = 0.f;
      #pragma unroll
      for (int ww = 0; ww < 8; ++ww) { dn += s_part[ww][hh][0]; ac += s_part[ww][hh][1 + d]; }
      s_swn[hh * D_ + d] = ac / dn;
    }
    __syncthreads();                 // (2)
    if (t < 136) {
      const int hh = t / D_, e = t - hh * D_;
      float s = bv[hh*D_ + e];
      #pragma unroll
      for (int d = 0; d < D_; ++d) s = fmaf(Wv[hh*289 + e*D_ + d], s_swn[hh*D_ + d], s);
      s_agg[hh*D_ + e] = s;
    }
    __syncthreads();                 // (3)
    if (t < 136) {
      const int o = t >> 3, pt = t & 7;
      float s = 0.f;
      #pragma unroll
      for (int jj = 0; jj < D_; ++jj) s = fmaf(Wo[o*136 + pt*D_ + jj], s_agg[pt*D_ + jj], s);
      s_wp[t] = s;
    }
    __syncthreads();                 // (4)
    if (t < D_) {
      float s = bo[t];
      #pragma unroll
      for (int pt = 0; pt < 8; ++pt) s += s_wp[t*8 + pt];
      comb[(b0 + j)*26 + t] = s;
    } else if (t < 26) {
      comb[(b0 + j)*26 + t] = x[(size_t)(b0 + j) * XROW + (t - D_)];   // special
    }
    __syncthreads();                 // (5) buf[(j+1)&1] complete; s_part/s_swn reusable
  }
}

// ---------------- Kernel 3: fused policy+value MLPs, LDS-free layer 2 ----------------
// Grid 256 x 512 thr, 8 batches/block. t = p(1)|kq(2)|lane(6). Layer-1 output i=kq*64+lane
// stays in REGISTERS (h[8]); layer-2 wave (p,kq) consumes exactly its own k-slice via
// v_readlane broadcast (zero LDS ops). 4-output x 8-batch register tile; kq-reduce in LDS.
__global__ __launch_bounds__(512, 2) void mlp_kernel(
    const float* __restrict__ comb,
    const float* __restrict__ pW1, const float* __restrict__ pb1,
    const float* __restrict__ pW2t, const float* __restrict__ pb2,
    const float* __restrict__ pW3, const float* __restrict__ pb3,
    const float* __restrict__ vW1, const float* __restrict__ vb1,
    const float* __restrict__ vW2t, const float* __restrict__ vb2,
    const float* __restrict__ vW3, const float* __restrict__ vb3,
    float* __restrict__ out)
{
  __shared__ float s_comb[8][26];
  __shared__ __align__(16) float s_red[2][3][8][HID_];   // kq=1..3 partials
  __shared__ __align__(16) float s_h2[2][8][HID_];

  const int t = threadIdx.x;
  const int b0 = blockIdx.x * 8;
  const int p = t >> 8;
  const int kq = (t >> 6) & 3;
  const int ln = t & 63;

  if (t < 208) { const int bb = t / 26, k = t - bb*26; s_comb[bb][k] = comb[(size_t)(b0 + bb)*26 + k]; }
  __syncthreads();

  const float* W1  = p ? vW1  : pW1;   const float* B1 = p ? vb1 : pb1;
  const float* W2t = p ? vW2t : pW2t;  const float* B2 = p ? vb2 : pb2;

  // ---- layer 1: output i = kq*64+ln for 8 batches, kept in registers
  float h[8];
  {
    const int i = kq * 64 + ln;
    float a[8];
    #pragma unroll
    for (int bb = 0; bb < 8; ++bb) a[bb] = 0.f;
    const float* wr = W1 + i * 26;
    for (int k = 0; k < 26; ++k) {
      const float wk = wr[k];
      #pragma unroll
      for (int bb = 0; bb < 8; ++bb) a[bb] = fmaf(wk, s_comb[bb][k], a[bb]);
    }
    const float bias = B1[i];
    #pragma unroll
    for (int bb = 0; bb < 8; ++bb) h[bb] = fmaxf(a[bb] + bias, 0.f);
  }

  // ---- layer 2: k-slice [kq*64, +64); h1[bb][kq*64+jj] lives in lane jj of THIS wave
  float4 acc[8];
  #pragma unroll
  for (int bb = 0; bb < 8; ++bb) acc[bb] = make_float4(0.f, 0.f, 0.f, 0.f);
  {
    const float* wbase = W2t + (size_t)(kq * 64) * HID_ + 4 * ln;
    #pragma unroll 8
    for (int jj = 0; jj < 64; ++jj) {
      const float4 wv = *(const float4*)(wbase + (size_t)jj * HID_);
      #pragma unroll
      for (int bb = 0; bb < 8; ++bb) {
        const float hv = bclane(h[bb], jj);     // wave-uniform broadcast, no LDS
        acc[bb].x = fmaf(wv.x, hv, acc[bb].x);
        acc[bb].y = fmaf(wv.y, hv, acc[bb].y);
        acc[bb].z = fmaf(wv.z, hv, acc[bb].z);
        acc[bb].w = fmaf(wv.w, hv, acc[bb].w);
      }
    }
  }
  if (kq > 0) {
    #pragma unroll
    for (int bb = 0; bb < 8; ++bb) *(float4*)&s_red[p][kq - 1][bb][4 * ln] = acc[bb];
  }
  __syncthreads();
  if (kq == 0) {
    const float4 bias = *(const float4*)&B2[4 * ln];
    #pragma unroll
    for (int bb = 0; bb < 8; ++bb) {
      const float4 r0 = *(const float4*)&s_red[p][0][bb][4 * ln];
      const float4 r1 = *(const float4*)&s_red[p][1][bb][4 * ln];
      const float4 r2 = *(const float4*)&s_red[p][2][bb][4 * ln];
      float4 r;
      r.x = fmaxf(acc[bb].x + r0.x + r1.x + r2.x + bias.x, 0.f);
      r.y = fmaxf(acc[bb].y + r0.y + r1.y + r2.y + bias.y, 0.f);
      r.z = fmaxf(acc[bb].z + r0.z + r1.z + r2.z + bias.z, 0.f);
      r.w = fmaxf(acc[bb].w + r0.w + r1.w + r2.w + bias.w, 0.f);
      *(float4*)&s_h2[p][bb][4 * ln] = r;
    }
  }
  __syncthreads();

  // ---- layer 3
  if (t < 184) {                        // policy: 8 batches x 23 outputs
    const int bb = t / OUT_, o = t - bb * OUT_;
    const float4* w4 = (const float4*)(pW3 + o * HID_);
    const float4* h4 = (const float4*)&s_h2[0][bb][0];
    float s = pb3[o];
    for (int k = 0; k < 64; ++k) {
      const float4 wv = w4[k], hv = h4[k];
      s = fmaf(wv.x, hv.x, fmaf(wv.y, hv.y, fmaf(wv.z, hv.z, fmaf(wv.w, hv.w, s))));
    }
    out[(size_t)(b0 + bb) * OUT_ + o] = s;
  } else if (t >= 256 && t < 264) {     // value: 8 batches x 1 output
    const int bb = t - 256;
    const float4* w4 = (const float4*)vW3;
    const float4* h4 = (const float4*)&s_h2[1][bb][0];
    float s = vb3[0];
    for (int k = 0; k < 64; ++k) {
      const float4 wv = w4[k], hv = h4[k];
      s = fmaf(wv.x, hv.x, fmaf(wv.y, hv.y, fmaf(wv.z, hv.z, fmaf(wv.w, hv.w, s))));
    }
    out[(size_t)B_ * OUT_ + b0 + bb] = s;
  }
}

extern "C" void kernel_launch(void* const* d_in, const int* in_sizes, int n_in,
                              void* d_out, int out_size, void* d_ws, size_t ws_size,
                              hipStream_t stream) {
  (void)in_sizes; (void)n_in; (void)out_size; (void)ws_size;
  const float* x   = (const float*)d_in[0];
  const float* Wk  = (const float*)d_in[1];
  const float* bk  = (const float*)d_in[2];
  const float* Wv  = (const float*)d_in[3];
  const float* bv  = (const float*)d_in[4];
  const float* q   = (const float*)d_in[5];
  const float* Wo  = (const float*)d_in[6];
  const float* bo  = (const float*)d_in[7];
  const float* pW1 = (const float*)d_in[8];
  const float* pb1 = (const float*)d_in[9];
  const float* pW2 = (const float*)d_in[10];
  const float* pb2 = (const float*)d_in[11];
  const float* pW3 = (const float*)d_in[12];
  const float* pb3 = (const float*)d_in[13];
  const float* vW1 = (const float*)d_in[14];
  const float* vb1 = (const float*)d_in[15];
  const float* vW2 = (const float*)d_in[16];
  const float* vb2 = (const float*)d_in[17];
  const float* vW3 = (const float*)d_in[18];
  const float* vb3 = (const float*)d_in[19];
  float* out = (float*)d_out;

  // workspace: comb (2048*26) | pW2t (65536) | vW2t (65536) | qkc (144) floats
  float* comb = (float*)d_ws;
  float* pW2t = comb + (size_t)B_ * 26;
  float* vW2t = pW2t + (size_t)HID_ * HID_;
  float* qkc  = vW2t + (size_t)HID_ * HID_;

  prep_kernel<<<129, 256, 0, stream>>>(pW2, vW2, Wk, bk, q, pW2t, vW2t, qkc);
  attn_comb_kernel<<<B_ / NB, 512, 0, stream>>>(x, qkc, Wv, bv, Wo, bo, comb);
  mlp_kernel<<<B_ / 8, 512, 0, stream>>>(comb, pW1, pb1, pW2t, pb2, pW3, pb3,
                                         vW1, vb1, vW2t, vb2, vW3, vb3, out);
}

// Round 9
// 57.385 us; speedup vs baseline: 1.2281x; 1.2281x over previous
//
#include <hip/hip_runtime.h>
#include <hip/hip_bf16.h>

#define B_ 2048
#define D_ 17
#define H_ 8
#define HID_ 256
#define OUT_ 23
#define XROW 8721       /* 513*17 floats per batch */

__device__ __forceinline__ float4 ld4u(const float* p) {   // 4B-aligned 16B load
  float4 v; __builtin_memcpy(&v, p, 16); return v;
}
__device__ __forceinline__ float bclane(float v, int l) {  // wave broadcast via readlane
  return __uint_as_float(__builtin_amdgcn_readlane(__float_as_uint(v), l));
}

// ---------------- Kernel 1: prep — transpose W2s + fold q into Wk ----------------
__global__ __launch_bounds__(256) void prep_kernel(
    const float* __restrict__ pW2, const float* __restrict__ vW2,
    const float* __restrict__ Wk, const float* __restrict__ bk,
    const float* __restrict__ q,
    float* __restrict__ pW2t, float* __restrict__ vW2t, float* __restrict__ qkc)
{
  const int bid = blockIdx.x;
  const int t = threadIdx.x;
  if (bid == 128) {
    if (t < H_ * D_) {
      const int h = t / D_, dd = t - h * D_;
      float s = 0.f;
      #pragma unroll
      for (int e = 0; e < D_; ++e) s = fmaf(Wk[h*289 + e*D_ + dd], q[h*D_ + e], s);
      qkc[h*18 + dd] = s;
    } else if (t < H_ * D_ + H_) {
      const int h = t - H_ * D_;
      float s = 0.f;
      #pragma unroll
      for (int e = 0; e < D_; ++e) s = fmaf(bk[h*D_ + e], q[h*D_ + e], s);
      qkc[h*18 + 17] = s;
    }
    return;
  }
  __shared__ float tile[32][33];
  const int m = bid >> 6, tid = bid & 63;
  const int ti = (tid >> 3) * 32, tk = (tid & 7) * 32;
  const float* src = m ? vW2 : pW2;
  float* dst = m ? vW2t : pW2t;
  const int tx = t & 31, ty = t >> 5;
  #pragma unroll
  for (int r = 0; r < 4; ++r) tile[ty + 8*r][tx] = src[(ti + ty + 8*r)*HID_ + tk + tx];
  __syncthreads();
  #pragma unroll
  for (int r = 0; r < 4; ++r) dst[(tk + ty + 8*r)*HID_ + ti + tx] = tile[tx][ty + 8*r];
}

// ---------------- Kernel 2: attention partials, 1 wave / (batch, quarter) ----------------
// Grid 8192 = (b<<2)|q. 64 thr. lane = (head=l&7, rowgroup=l>>3). Zero LDS, zero barriers.
// Probe 16 chunk-heads -> nch live 8-row chunks; double-buffered register stream;
// shfl-reduce over rowgroups; lanes 0-7 write (den, acc[17]) to part[bid][h*18..].
__global__ __launch_bounds__(64) void attn_part_kernel(
    const float* __restrict__ x, const float* __restrict__ qkc,
    float* __restrict__ part)
{
  const int bid = blockIdx.x;
  const int b = bid >> 2, q = bid & 3;
  const int lane = threadIdx.x;
  const int h = lane & 7, rg = lane >> 3;
  const float* xs = x + (size_t)b * XROW + D_;
  const int r0 = q * 128;

  // probe: word0 of rows r0 + 8*(lane&15)  (masked rows are exact zeros; live word0==0 P~1e-45)
  const float w0 = xs[(size_t)(r0 + 8 * (lane & 15)) * D_];
  const unsigned long long lv = __ballot((lane < 16) && (w0 != 0.f));
  const int nch = lv ? (64 - __builtin_clzll(lv)) : 0;   // live chunks (8 rows each)

  float qk[D_];
  #pragma unroll
  for (int d = 0; d < D_; ++d) qk[d] = qkc[h*18 + d];
  const float chr = qkc[h*18 + 17];

  float den = 0.f, acc[D_];
  #pragma unroll
  for (int d = 0; d < D_; ++d) acc[d] = 0.f;

  if (nch) {
    const float* rb = xs + (size_t)(r0 + rg) * D_;
    float4 A0, A1, A2, A3; float A4;
    float4 C0, C1, C2, C3; float C4;
    auto loadA = [&](int g) {
      const float* rp = rb + g * 136;
      A0 = ld4u(rp); A1 = ld4u(rp+4); A2 = ld4u(rp+8); A3 = ld4u(rp+12); A4 = rp[16];
    };
    auto loadC = [&](int g) {
      const float* rp = rb + g * 136;
      C0 = ld4u(rp); C1 = ld4u(rp+4); C2 = ld4u(rp+8); C3 = ld4u(rp+12); C4 = rp[16];
    };
    auto comp = [&](const float4& v0, const float4& v1, const float4& v2, const float4& v3, float v4) {
      float sc = chr;
      sc = fmaf(qk[0],  v0.x, sc); sc = fmaf(qk[1],  v0.y, sc);
      sc = fmaf(qk[2],  v0.z, sc); sc = fmaf(qk[3],  v0.w, sc);
      sc = fmaf(qk[4],  v1.x, sc); sc = fmaf(qk[5],  v1.y, sc);
      sc = fmaf(qk[6],  v1.z, sc); sc = fmaf(qk[7],  v1.w, sc);
      sc = fmaf(qk[8],  v2.x, sc); sc = fmaf(qk[9],  v2.y, sc);
      sc = fmaf(qk[10], v2.z, sc); sc = fmaf(qk[11], v2.w, sc);
      sc = fmaf(qk[12], v3.x, sc); sc = fmaf(qk[13], v3.y, sc);
      sc = fmaf(qk[14], v3.z, sc); sc = fmaf(qk[15], v3.w, sc);
      sc = fmaf(qk[16], v4, sc);
      const float p = (v0.x != 0.f) ? __expf(sc) : 0.f;   // per-row mask
      den += p;
      acc[0]  = fmaf(p, v0.x, acc[0]);  acc[1]  = fmaf(p, v0.y, acc[1]);
      acc[2]  = fmaf(p, v0.z, acc[2]);  acc[3]  = fmaf(p, v0.w, acc[3]);
      acc[4]  = fmaf(p, v1.x, acc[4]);  acc[5]  = fmaf(p, v1.y, acc[5]);
      acc[6]  = fmaf(p, v1.z, acc[6]);  acc[7]  = fmaf(p, v1.w, acc[7]);
      acc[8]  = fmaf(p, v2.x, acc[8]);  acc[9]  = fmaf(p, v2.y, acc[9]);
      acc[10] = fmaf(p, v2.z, acc[10]); acc[11] = fmaf(p, v2.w, acc[11]);
      acc[12] = fmaf(p, v3.x, acc[12]); acc[13] = fmaf(p, v3.y, acc[13]);
      acc[14] = fmaf(p, v3.z, acc[14]); acc[15] = fmaf(p, v3.w, acc[15]);
      acc[16] = fmaf(p, v4, acc[16]);
    };

    loadA(0);
    #pragma unroll 1
    for (int g = 0; g < nch; g += 2) {
      if (g + 1 < nch) loadC(g + 1);
      comp(A0, A1, A2, A3, A4);
      if (g + 1 >= nch) break;
      if (g + 2 < nch) loadA(g + 2);
      comp(C0, C1, C2, C3, C4);
    }
  }

  // reduce over rowgroups (same-head lanes are stride-8)
  #pragma unroll
  for (int m = 8; m <= 32; m <<= 1) {
    den += __shfl_xor(den, m, 64);
    #pragma unroll
    for (int d = 0; d < D_; ++d) acc[d] += __shfl_xor(acc[d], m, 64);
  }
  if (lane < 8) {
    float* pp = part + (size_t)bid * 144 + lane * 18;
    pp[0] = den;
    #pragma unroll
    for (int d = 0; d < D_; ++d) pp[1 + d] = acc[d];
  }
}

// ---------------- Kernel 3: combine + fused policy/value MLPs ----------------
// Grid 256 x 512 thr, 8 batches/block. Prologue: part -> swn -> agg(Wv) -> Wo -> s_comb.
// Then R8's readlane mlp: layer-1 in regs, layer-2 via v_readlane broadcast (no LDS pipe).
__global__ __launch_bounds__(512) void mlp_fused_kernel(
    const float* __restrict__ x, const float* __restrict__ part,
    const float* __restrict__ Wv, const float* __restrict__ bv,
    const float* __restrict__ Wo, const float* __restrict__ bo,
    const float* __restrict__ pW1, const float* __restrict__ pb1,
    const float* __restrict__ pW2t, const float* __restrict__ pb2,
    const float* __restrict__ pW3, const float* __restrict__ pb3,
    const float* __restrict__ vW1, const float* __restrict__ vb1,
    const float* __restrict__ vW2t, const float* __restrict__ vb2,
    const float* __restrict__ vW3, const float* __restrict__ vb3,
    float* __restrict__ out)
{
  __shared__ float s_swn[8][136];
  __shared__ float s_agg[8][136];
  __shared__ float s_wp[8][136];
  __shared__ float s_comb[8][26];
  __shared__ __align__(16) float s_red[2][3][8][HID_];
  __shared__ __align__(16) float s_h2[2][8][HID_];

  const int t = threadIdx.x;
  const int b0 = blockIdx.x * 8;
  const int cb = t >> 6;          // combine-phase batch 0..7
  const int cl = t & 63;

  // ---- combine phase A: swn[h][d] = (sum_q acc) / (sum_q den)
  {
    const float* pb_ = part + (size_t)(b0 + cb) * 4 * 144;
    for (int u = cl; u < 136; u += 64) {
      const int hh = u / D_, d = u - hh * D_;
      const float dn = pb_[hh*18] + pb_[144 + hh*18] + pb_[288 + hh*18] + pb_[432 + hh*18];
      const float ac = pb_[hh*18+1+d] + pb_[144 + hh*18+1+d] + pb_[288 + hh*18+1+d] + pb_[432 + hh*18+1+d];
      s_swn[cb][u] = ac / dn;
    }
  }
  __syncthreads();
  // ---- B: agg = bv + Wv·swn
  for (int u = cl; u < 136; u += 64) {
    const int hh = u / D_, e = u - hh * D_;
    float s = bv[u];
    #pragma unroll
    for (int d = 0; d < D_; ++d) s = fmaf(Wv[hh*289 + e*D_ + d], s_swn[cb][hh*D_ + d], s);
    s_agg[cb][u] = s;
  }
  __syncthreads();
  // ---- C: Wo partials (17 outs x 8 k-parts)
  for (int u = cl; u < 136; u += 64) {
    const int o = u >> 3, pt = u & 7;
    float s = 0.f;
    #pragma unroll
    for (int j = 0; j < D_; ++j) s = fmaf(Wo[o*136 + pt*D_ + j], s_agg[cb][pt*D_ + j], s);
    s_wp[cb][u] = s;
  }
  __syncthreads();
  // ---- D: comb = [attn(17) | special(9)]
  if (cl < D_) {
    float s = bo[cl];
    #pragma unroll
    for (int pt = 0; pt < 8; ++pt) s += s_wp[cb][cl*8 + pt];
    s_comb[cb][cl] = s;
  } else if (cl < 26) {
    s_comb[cb][cl] = x[(size_t)(b0 + cb) * XROW + (cl - D_)];
  }
  __syncthreads();

  // ---- MLPs: t = p(1)|kq(2)|ln(6)
  const int p = t >> 8;
  const int kq = (t >> 6) & 3;
  const int ln = t & 63;
  const float* W1  = p ? vW1  : pW1;   const float* B1 = p ? vb1 : pb1;
  const float* W2t = p ? vW2t : pW2t;  const float* B2 = p ? vb2 : pb2;

  // layer 1: output i = kq*64+ln for 8 batches, kept in registers
  float h[8];
  {
    const int i = kq * 64 + ln;
    float a[8];
    #pragma unroll
    for (int bb = 0; bb < 8; ++bb) a[bb] = 0.f;
    const float* wr = W1 + i * 26;
    for (int k = 0; k < 26; ++k) {
      const float wk = wr[k];
      #pragma unroll
      for (int bb = 0; bb < 8; ++bb) a[bb] = fmaf(wk, s_comb[bb][k], a[bb]);
    }
    const float bias = B1[i];
    #pragma unroll
    for (int bb = 0; bb < 8; ++bb) h[bb] = fmaxf(a[bb] + bias, 0.f);
  }

  // layer 2: k-slice [kq*64, +64); h1[bb][kq*64+jj] lives in lane jj of THIS wave
  float4 acc[8];
  #pragma unroll
  for (int bb = 0; bb < 8; ++bb) acc[bb] = make_float4(0.f, 0.f, 0.f, 0.f);
  {
    const float* wbase = W2t + (size_t)(kq * 64) * HID_ + 4 * ln;
    #pragma unroll 8
    for (int jj = 0; jj < 64; ++jj) {
      const float4 wv = *(const float4*)(wbase + (size_t)jj * HID_);
      #pragma unroll
      for (int bb = 0; bb < 8; ++bb) {
        const float hv = bclane(h[bb], jj);
        acc[bb].x = fmaf(wv.x, hv, acc[bb].x);
        acc[bb].y = fmaf(wv.y, hv, acc[bb].y);
        acc[bb].z = fmaf(wv.z, hv, acc[bb].z);
        acc[bb].w = fmaf(wv.w, hv, acc[bb].w);
      }
    }
  }
  if (kq > 0) {
    #pragma unroll
    for (int bb = 0; bb < 8; ++bb) *(float4*)&s_red[p][kq - 1][bb][4 * ln] = acc[bb];
  }
  __syncthreads();
  if (kq == 0) {
    const float4 bias = *(const float4*)&B2[4 * ln];
    #pragma unroll
    for (int bb = 0; bb < 8; ++bb) {
      const float4 r0 = *(const float4*)&s_red[p][0][bb][4 * ln];
      const float4 r1 = *(const float4*)&s_red[p][1][bb][4 * ln];
      const float4 r2 = *(const float4*)&s_red[p][2][bb][4 * ln];
      float4 r;
      r.x = fmaxf(acc[bb].x + r0.x + r1.x + r2.x + bias.x, 0.f);
      r.y = fmaxf(acc[bb].y + r0.y + r1.y + r2.y + bias.y, 0.f);
      r.z = fmaxf(acc[bb].z + r0.z + r1.z + r2.z + bias.z, 0.f);
      r.w = fmaxf(acc[bb].w + r0.w + r1.w + r2.w + bias.w, 0.f);
      *(float4*)&s_h2[p][bb][4 * ln] = r;
    }
  }
  __syncthreads();

  // layer 3
  if (t < 184) {                        // policy: 8 batches x 23 outputs
    const int bb = t / OUT_, o = t - bb * OUT_;
    const float4* w4 = (const float4*)(pW3 + o * HID_);
    const float4* h4 = (const float4*)&s_h2[0][bb][0];
    float s = pb3[o];
    for (int k = 0; k < 64; ++k) {
      const float4 wv = w4[k], hv = h4[k];
      s = fmaf(wv.x, hv.x, fmaf(wv.y, hv.y, fmaf(wv.z, hv.z, fmaf(wv.w, hv.w, s))));
    }
    out[(size_t)(b0 + bb) * OUT_ + o] = s;
  } else if (t >= 256 && t < 264) {     // value: 8 batches x 1 output
    const int bb = t - 256;
    const float4* w4 = (const float4*)vW3;
    const float4* h4 = (const float4*)&s_h2[1][bb][0];
    float s = vb3[0];
    for (int k = 0; k < 64; ++k) {
      const float4 wv = w4[k], hv = h4[k];
      s = fmaf(wv.x, hv.x, fmaf(wv.y, hv.y, fmaf(wv.z, hv.z, fmaf(wv.w, hv.w, s))));
    }
    out[(size_t)B_ * OUT_ + b0 + bb] = s;
  }
}

extern "C" void kernel_launch(void* const* d_in, const int* in_sizes, int n_in,
                              void* d_out, int out_size, void* d_ws, size_t ws_size,
                              hipStream_t stream) {
  (void)in_sizes; (void)n_in; (void)out_size; (void)ws_size;
  const float* x   = (const float*)d_in[0];
  const float* Wk  = (const float*)d_in[1];
  const float* bk  = (const float*)d_in[2];
  const float* Wv  = (const float*)d_in[3];
  const float* bv  = (const float*)d_in[4];
  const float* q   = (const float*)d_in[5];
  const float* Wo  = (const float*)d_in[6];
  const float* bo  = (const float*)d_in[7];
  const float* pW1 = (const float*)d_in[8];
  const float* pb1 = (const float*)d_in[9];
  const float* pW2 = (const float*)d_in[10];
  const float* pb2 = (const float*)d_in[11];
  const float* pW3 = (const float*)d_in[12];
  const float* pb3 = (const float*)d_in[13];
  const float* vW1 = (const float*)d_in[14];
  const float* vb1 = (const float*)d_in[15];
  const float* vW2 = (const float*)d_in[16];
  const float* vb2 = (const float*)d_in[17];
  const float* vW3 = (const float*)d_in[18];
  const float* vb3 = (const float*)d_in[19];
  float* out = (float*)d_out;

  // workspace: pW2t (65536) | vW2t (65536) | qkc (144) | part (8192*144) floats
  float* pW2t = (float*)d_ws;
  float* vW2t = pW2t + (size_t)HID_ * HID_;
  float* qkc  = vW2t + (size_t)HID_ * HID_;
  float* part = qkc + 160;

  prep_kernel<<<129, 256, 0, stream>>>(pW2, vW2, Wk, bk, q, pW2t, vW2t, qkc);
  attn_part_kernel<<<B_ * 4, 64, 0, stream>>>(x, qkc, part);
  mlp_fused_kernel<<<B_ / 8, 512, 0, stream>>>(x, part, Wv, bv, Wo, bo,
                                               pW1, pb1, pW2t, pb2, pW3, pb3,
                                               vW1, vb1, vW2t, vb2, vW3, vb3, out);
}